// Round 2
// baseline (371.306 us; speedup 1.0000x reference)
//
#include <hip/hip_runtime.h>
#include <stdint.h>

#define NN   2048
#define DD   128
#define DIN  256
#define ROWZ 75

typedef float f32x4 __attribute__((ext_vector_type(4)));
typedef short bf16x8 __attribute__((ext_vector_type(8)));
typedef unsigned int u32x4 __attribute__((ext_vector_type(4)));
typedef unsigned int u32x2 __attribute__((ext_vector_type(2)));

__device__ __forceinline__ unsigned short f2bf(float x){
  union { float f; unsigned int u; } v; v.f = x;
  unsigned int u = v.u;
  u += 0x7fffu + ((u >> 16) & 1u);   // RNE
  return (unsigned short)(u >> 16);
}
__device__ __forceinline__ float bf2f(unsigned short b){
  union { float f; unsigned int u; } v; v.u = ((unsigned int)b) << 16;
  return v.f;
}

// ---------------------------------------------------------------------------
// Kernel A: Wh = h @ W  (fp32), row L2 norms.
// Outputs: whn  = bf16 normalized, row-major [16384][128]   (QK operands)
//          whT  = bf16 unnormalized, transposed [8][128][2048] (PV V^T staging)
// Block: 256 threads, 64 rows. Thread: 8 rows x 4 d register tile.
// ---------------------------------------------------------------------------
__launch_bounds__(256, 2)
__global__ void wh_kernel(const float* __restrict__ h, const float* __restrict__ W,
                          unsigned short* __restrict__ whn, unsigned short* __restrict__ whT)
{
  __shared__ float hs[32][64];     // [k][row] transposed h tile
  __shared__ float Ws[32][128];
  __shared__ float ssp[64][33];    // padded: avoid bank conflict in reduce
  __shared__ float sinv[64];

  const int t  = threadIdx.x;
  const int r0 = blockIdx.x * 64;        // global row base (within one batch: 64 | 2048)
  const int r8 = (t >> 5) * 8;           // row sub-base 0..56
  const int d4 = (t & 31) * 4;           // d sub-base 0..124

  float acc[8][4];
#pragma unroll
  for (int i = 0; i < 8; ++i)
#pragma unroll
    for (int j = 0; j < 4; ++j) acc[i][j] = 0.f;

  const int lrow = t >> 2;         // 0..63
  const int lkb  = (t & 3) * 8;    // 0,8,16,24

  for (int kt = 0; kt < 8; ++kt){
    __syncthreads();
    { // stage h tile transposed: hs[k][row]
      const float* src = h + (size_t)(r0 + lrow) * DIN + kt * 32 + lkb;
      f32x4 a = *(const f32x4*)src;
      f32x4 c = *(const f32x4*)(src + 4);
#pragma unroll
      for (int e = 0; e < 4; ++e){ hs[lkb + e][lrow] = a[e]; hs[lkb + 4 + e][lrow] = c[e]; }
    }
    { // stage W tile
      const int k = t >> 3;
      const int d = (t & 7) * 16;
      const float* src = W + (size_t)(kt * 32 + k) * DD + d;
      float* dst = &Ws[k][d];
#pragma unroll
      for (int e = 0; e < 4; ++e) ((f32x4*)dst)[e] = ((const f32x4*)src)[e];
    }
    __syncthreads();
#pragma unroll
    for (int k = 0; k < 32; ++k){
      f32x4 w4 = *(const f32x4*)&Ws[k][d4];
      f32x4 ha = *(const f32x4*)&hs[k][r8];
      f32x4 hb = *(const f32x4*)&hs[k][r8 + 4];
#pragma unroll
      for (int i = 0; i < 4; ++i)
#pragma unroll
        for (int j = 0; j < 4; ++j){
          acc[i][j]     += ha[i] * w4[j];
          acc[4 + i][j] += hb[i] * w4[j];
        }
    }
  }

  // row norms: partial sums over this thread's 4 d
#pragma unroll
  for (int i = 0; i < 8; ++i){
    float s = acc[i][0]*acc[i][0] + acc[i][1]*acc[i][1]
            + acc[i][2]*acc[i][2] + acc[i][3]*acc[i][3];
    ssp[r8 + i][t & 31] = s;
  }
  __syncthreads();
  if (t < 64){
    float ss = 0.f;
#pragma unroll
    for (int c = 0; c < 32; ++c) ss += ssp[t][c];
    sinv[t] = 1.0f / fmaxf(sqrtf(ss), 1e-12f);   // F.normalize eps semantics
  }
  __syncthreads();

  const int bb = r0 >> 11;
  const int n0 = (r0 & 2047) + r8;

  // whn: normalized bf16, row-major (8B store per row)
#pragma unroll
  for (int i = 0; i < 8; ++i){
    const float inv = sinv[r8 + i];
    unsigned int lo = (unsigned int)f2bf(acc[i][0]*inv) | ((unsigned int)f2bf(acc[i][1]*inv) << 16);
    unsigned int hi = (unsigned int)f2bf(acc[i][2]*inv) | ((unsigned int)f2bf(acc[i][3]*inv) << 16);
    u32x2 pk = { lo, hi };
    *(u32x2*)(whn + (size_t)(r0 + r8 + i) * DD + d4) = pk;
  }
  // whT: unnormalized bf16, transposed [b][d][n] (16B store per d)
#pragma unroll
  for (int j = 0; j < 4; ++j){
    u32x4 pk;
#pragma unroll
    for (int e = 0; e < 4; ++e)
      pk[e] = (unsigned int)f2bf(acc[2*e][j]) | ((unsigned int)f2bf(acc[2*e + 1][j]) << 16);
    *(u32x4*)(whT + ((size_t)(bb * DD + d4 + j)) * NN + n0) = pk;
  }
}

// ---------------------------------------------------------------------------
// Kernel B: fused score -> mask/row-zero -> softmax(no-max) -> PV -> ELU.
// Block: 256 threads (4 waves), 32 Q rows. Iterates m in chunks of 128.
// Wave w owns m-subchunk [w*32, w*32+32) for QK/P, and d rows [w*32,+32) for
// V^T staging. V^T staged via global_load_lds with xor-granule swizzle so
// b128 fragment reads are bank-conflict-free.
// ---------------------------------------------------------------------------
__launch_bounds__(256, 2)
__global__ void attn_kernel(const unsigned short* __restrict__ whn,
                            const unsigned short* __restrict__ whT,
                            const int* __restrict__ adj,
                            float* __restrict__ out)
{
  __shared__ unsigned short Vt[128 * 128];      // 32 KB: V^T tile, swizzled granules
  __shared__ unsigned short Pbuf[4][32 * 40];   // 10 KB: per-wave P (stride 40 = 16B-aligned rows)
  __shared__ float linv_s[32];

  const int t    = threadIdx.x;
  const int w    = t >> 6;
  const int l    = t & 63;
  const int quad = l >> 4;
  const int l16  = l & 15;
  const int b    = blockIdx.x >> 6;
  const int qbase = (blockIdx.x & 63) * 32;

  const unsigned short* whn_b = whn + (size_t)b * NN * DD;
  const unsigned short* whT_b = whT + (size_t)b * DD * NN;
  const int*            adj_b = adj + (size_t)b * NN * NN;

  // Q fragments (A-layout: row = lane&15, k = quad*8 + j), held all loop
  bf16x8 qf[2][4];
#pragma unroll
  for (int s = 0; s < 2; ++s)
#pragma unroll
    for (int kc = 0; kc < 4; ++kc)
      qf[s][kc] = *(const bf16x8*)(whn_b + (size_t)(qbase + s*16 + l16) * DD + kc*32 + quad*8);

  f32x4 oacc[2][8];
  float lacc[2][4];
#pragma unroll
  for (int s = 0; s < 2; ++s){
#pragma unroll
    for (int dt = 0; dt < 8; ++dt) oacc[s][dt] = (f32x4){0.f, 0.f, 0.f, 0.f};
#pragma unroll
    for (int r = 0; r < 4; ++r) lacc[s][r] = 0.f;
  }

  unsigned short* const Pw = &Pbuf[w][0];

  for (int it = 0; it < 16; ++it){
    const int m0 = it * 128;
    __syncthreads();   // prev iter's Vt reads done before DMA overwrite

    // ---- stage V^T tile via async global->LDS (16B/lane, 4 d-rows/instr) ----
#pragma unroll
    for (int ii = 0; ii < 8; ++ii){
      const int d   = w*32 + ii*4 + quad;          // this lane's d row
      const int gsw = l16 ^ (d & 7);               // xor granule swizzle
      const unsigned short* src = whT_b + (size_t)d * NN + m0 + gsw * 8;
      __builtin_amdgcn_global_load_lds(
          (const __attribute__((address_space(1))) void*)src,
          (__attribute__((address_space(3))) void*)&Vt[(w*32 + ii*4) * 128],
          16, 0, 0);
    }

    // ---- QK + mask + exp -> P (overlaps the DMA) ----
#pragma unroll
    for (int f = 0; f < 2; ++f){
      const int mrow = m0 + w*32 + f*16 + l16;     // B-operand col (= m), and C col
      bf16x8 kf[4];
#pragma unroll
      for (int kc = 0; kc < 4; ++kc)
        kf[kc] = *(const bf16x8*)(whn_b + (size_t)mrow * DD + kc*32 + quad*8);
#pragma unroll
      for (int s = 0; s < 2; ++s){
        f32x4 sc = (f32x4){0.f, 0.f, 0.f, 0.f};
#pragma unroll
        for (int kc = 0; kc < 4; ++kc)
          sc = __builtin_amdgcn_mfma_f32_16x16x32_bf16(qf[s][kc], kf[kc], sc, 0, 0, 0);
#pragma unroll
        for (int r = 0; r < 4; ++r){
          const int qrow = qbase + s*16 + quad*4 + r;       // C row
          float sv = (qrow < ROWZ) ? 0.f : sc[r];           // row-zeroing bug emulation
          const int av = adj_b[(size_t)qrow * NN + mrow];
          unsigned short pb = 0;
          float p32 = 0.f;
          if (av > 0){ pb = f2bf(__expf(sv)); p32 = bf2f(pb); }
          lacc[s][r] += p32;
          Pw[(s*16 + quad*4 + r) * 40 + f*16 + l16] = pb;   // C-layout -> LDS
        }
      }
    }
    __syncthreads();   // drains vmcnt: Vt ready; P visible (wave-local anyway)

    // ---- PV: out += P[16x32] * V[32x128] per q-subtile ----
#pragma unroll
    for (int s = 0; s < 2; ++s){
      bf16x8 pfr = *(const bf16x8*)&Pw[(s*16 + l16) * 40 + quad*8];  // A-layout read
#pragma unroll
      for (int dt = 0; dt < 8; ++dt){
        const int d  = dt*16 + l16;
        const int gg = (w*4 + quad) ^ (d & 7);
        bf16x8 vf = *(const bf16x8*)&Vt[d * 128 + gg * 8];
        oacc[s][dt] = __builtin_amdgcn_mfma_f32_16x16x32_bf16(pfr, vf, oacc[s][dt], 0, 0, 0);
      }
    }
  }

  // ---- l reduction (reuse own wave's Pbuf region as float scratch) ----
  {
    float* lredw = (float*)Pw;
#pragma unroll
    for (int s = 0; s < 2; ++s)
#pragma unroll
      for (int r = 0; r < 4; ++r)
        lredw[(s*16 + quad*4 + r) * 16 + l16] = lacc[s][r];
  }
  __syncthreads();
  if (t < 32){
    float sum = 0.f;
    for (int ww = 0; ww < 4; ++ww){
      const float* lr = (const float*)&Pbuf[ww][0];
#pragma unroll
      for (int c = 0; c < 16; ++c) sum += lr[t * 16 + c];
    }
    linv_s[t] = 1.0f / sum;
  }

  // ---- output reduction across waves (reuse Vt as 32KB float scratch) ----
  float* const ored = (float*)&Vt[0];
  for (int s = 0; s < 2; ++s){
    __syncthreads();   // linv visible / previous pass reads done
#pragma unroll
    for (int dt = 0; dt < 8; ++dt)
#pragma unroll
      for (int r = 0; r < 4; ++r)
        ored[w*2048 + (quad*4 + r)*128 + dt*16 + l16] = oacc[s][dt][r];
    __syncthreads();
#pragma unroll
    for (int j = 0; j < 8; ++j){
      const int o  = j*256 + t;
      const int ql = o >> 7, d = o & 127;
      float v = ored[ql*128 + d] + ored[2048 + ql*128 + d]
              + ored[4096 + ql*128 + d] + ored[6144 + ql*128 + d];
      v *= linv_s[s*16 + ql];
      v = (v > 0.f) ? v : expm1f(v);   // ELU (alpha=1)
      out[(size_t)(b*NN + qbase + s*16 + ql) * DD + d] = v;
    }
  }
}

extern "C" void kernel_launch(void* const* d_in, const int* in_sizes, int n_in,
                              void* d_out, int out_size, void* d_ws, size_t ws_size,
                              hipStream_t stream)
{
  const float* h       = (const float*)d_in[0];
  // d_in[1] = adj  (unused by the reference)
  const int*   adj_eye = (const int*)d_in[2];
  const float* W       = (const float*)d_in[3];
  float*       out     = (float*)d_out;

  unsigned short* whn = (unsigned short*)d_ws;                    // 16384*128 bf16 = 4 MB
  unsigned short* whT = whn + (size_t)16384 * 128;                // 8*128*2048 bf16 = 4 MB

  wh_kernel<<<256, 256, 0, stream>>>(h, W, whn, whT);
  attn_kernel<<<512, 256, 0, stream>>>(whn, whT, adj_eye, out);
}

// Round 3
// 298.545 us; speedup vs baseline: 1.2437x; 1.2437x over previous
//
#include <hip/hip_runtime.h>
#include <stdint.h>

#define NN   2048
#define DD   128
#define DIN  256
#define ROWZ 75

typedef float f32x4 __attribute__((ext_vector_type(4)));
typedef short bf16x8 __attribute__((ext_vector_type(8)));
typedef unsigned int u32x4 __attribute__((ext_vector_type(4)));
typedef unsigned int u32x2 __attribute__((ext_vector_type(2)));

__device__ __forceinline__ unsigned short f2bf(float x){
  union { float f; unsigned int u; } v; v.f = x;
  unsigned int u = v.u;
  u += 0x7fffu + ((u >> 16) & 1u);   // RNE
  return (unsigned short)(u >> 16);
}
__device__ __forceinline__ float bf2f(unsigned short b){
  union { float f; unsigned int u; } v; v.u = ((unsigned int)b) << 16;
  return v.f;
}

// ---------------------------------------------------------------------------
// Kernel A: Wh = h @ W (fp32), row L2 norms.
// 512 blocks x 32 rows (2 blocks/CU, 2 waves/SIMD — R2 version had 1 wave/SIMD).
// hs padded to 36 floats/row: 16B-aligned rows + <=4-way store conflicts.
// ---------------------------------------------------------------------------
__launch_bounds__(256, 2)
__global__ void wh_kernel(const float* __restrict__ h, const float* __restrict__ W,
                          unsigned short* __restrict__ whn, unsigned short* __restrict__ whT)
{
  __shared__ float hs[32][36];     // [k][row], pad 4: aligned + fewer bank conflicts
  __shared__ float Ws[32][128];
  __shared__ float ssp[32][33];
  __shared__ float sinv[32];

  const int t  = threadIdx.x;
  const int r0 = blockIdx.x * 32;        // global row base
  const int r4 = (t >> 5) * 4;           // row sub-base 0..28
  const int d4 = (t & 31) * 4;           // d sub-base 0..124

  float acc[4][4];
#pragma unroll
  for (int i = 0; i < 4; ++i)
#pragma unroll
    for (int j = 0; j < 4; ++j) acc[i][j] = 0.f;

  const int lrow = t >> 3;         // 0..31
  const int lkb  = (t & 7) * 4;    // 0,4,...,28

  for (int kt = 0; kt < 8; ++kt){
    __syncthreads();
    { // stage h tile transposed: hs[k][row]
      const float* src = h + (size_t)(r0 + lrow) * DIN + kt * 32 + lkb;
      f32x4 a = *(const f32x4*)src;
#pragma unroll
      for (int e = 0; e < 4; ++e) hs[lkb + e][lrow] = a[e];
    }
    { // stage W tile
      const int k = t >> 3;
      const int d = (t & 7) * 16;
      const float* src = W + (size_t)(kt * 32 + k) * DD + d;
      float* dst = &Ws[k][d];
#pragma unroll
      for (int e = 0; e < 4; ++e) ((f32x4*)dst)[e] = ((const f32x4*)src)[e];
    }
    __syncthreads();
#pragma unroll
    for (int k = 0; k < 32; ++k){
      f32x4 w4 = *(const f32x4*)&Ws[k][d4];
      f32x4 ha = *(const f32x4*)&hs[k][r4];
#pragma unroll
      for (int i = 0; i < 4; ++i)
#pragma unroll
        for (int j = 0; j < 4; ++j)
          acc[i][j] += ha[i] * w4[j];
    }
  }

  // row norms
#pragma unroll
  for (int i = 0; i < 4; ++i){
    float s = acc[i][0]*acc[i][0] + acc[i][1]*acc[i][1]
            + acc[i][2]*acc[i][2] + acc[i][3]*acc[i][3];
    ssp[r4 + i][t & 31] = s;
  }
  __syncthreads();
  if (t < 32){
    float ss = 0.f;
#pragma unroll
    for (int c = 0; c < 32; ++c) ss += ssp[t][c];
    sinv[t] = 1.0f / fmaxf(sqrtf(ss), 1e-12f);   // F.normalize eps semantics
  }
  __syncthreads();

  const int bb = r0 >> 11;
  const int n0 = (r0 & 2047) + r4;

  // whn: normalized bf16, row-major
#pragma unroll
  for (int i = 0; i < 4; ++i){
    const float inv = sinv[r4 + i];
    unsigned int lo = (unsigned int)f2bf(acc[i][0]*inv) | ((unsigned int)f2bf(acc[i][1]*inv) << 16);
    unsigned int hi = (unsigned int)f2bf(acc[i][2]*inv) | ((unsigned int)f2bf(acc[i][3]*inv) << 16);
    u32x2 pk = { lo, hi };
    *(u32x2*)(whn + (size_t)(r0 + r4 + i) * DD + d4) = pk;
  }
  // whT: unnormalized bf16, transposed [b][d][n] (8B store per d)
#pragma unroll
  for (int j = 0; j < 4; ++j){
    u32x2 pk;
#pragma unroll
    for (int e = 0; e < 2; ++e)
      pk[e] = (unsigned int)f2bf(acc[2*e][j]) | ((unsigned int)f2bf(acc[2*e + 1][j]) << 16);
    *(u32x2*)(whT + ((size_t)(bb * DD + d4 + j)) * NN + n0) = pk;
  }
}

// ---------------------------------------------------------------------------
// Kernel B: fused score -> mask/row-zero -> softmax(no-max) -> PV -> ELU.
// R3 change: adj loads register-prefetched one full m-iteration ahead and
// batched (R2 interleaved them with uses -> ~2 outstanding misses/wave ->
// 672 GB/s latency-serialized). kf loads for both f batched upfront too.
// ---------------------------------------------------------------------------
__launch_bounds__(256, 2)
__global__ void attn_kernel(const unsigned short* __restrict__ whn,
                            const unsigned short* __restrict__ whT,
                            const int* __restrict__ adj,
                            float* __restrict__ out)
{
  __shared__ unsigned short Vt[128 * 128];      // 32 KB: V^T tile, swizzled granules
  __shared__ unsigned short Pbuf[4][32 * 40];   // 10 KB: per-wave P (stride 40 = 16B-aligned rows)
  __shared__ float linv_s[32];

  const int t    = threadIdx.x;
  const int w    = t >> 6;
  const int l    = t & 63;
  const int quad = l >> 4;
  const int l16  = l & 15;
  const int b    = blockIdx.x >> 6;
  const int qbase = (blockIdx.x & 63) * 32;

  const unsigned short* whn_b = whn + (size_t)b * NN * DD;
  const unsigned short* whT_b = whT + (size_t)b * DD * NN;
  const int*            adj_b = adj + (size_t)b * NN * NN;

  // Q fragments (A-layout: row = lane&15, k = quad*8 + j), held all loop
  bf16x8 qf[2][4];
#pragma unroll
  for (int s = 0; s < 2; ++s)
#pragma unroll
    for (int kc = 0; kc < 4; ++kc)
      qf[s][kc] = *(const bf16x8*)(whn_b + (size_t)(qbase + s*16 + l16) * DD + kc*32 + quad*8);

  f32x4 oacc[2][8];
  float lacc[2][4];
#pragma unroll
  for (int s = 0; s < 2; ++s){
#pragma unroll
    for (int dt = 0; dt < 8; ++dt) oacc[s][dt] = (f32x4){0.f, 0.f, 0.f, 0.f};
#pragma unroll
    for (int r = 0; r < 4; ++r) lacc[s][r] = 0.f;
  }

  unsigned short* const Pw = &Pbuf[w][0];

  // adj values for iteration 0, batched (16 independent dword loads in flight)
  int av[2][2][4];
#pragma unroll
  for (int f = 0; f < 2; ++f)
#pragma unroll
    for (int s = 0; s < 2; ++s)
#pragma unroll
      for (int r = 0; r < 4; ++r)
        av[f][s][r] = adj_b[(size_t)(qbase + s*16 + quad*4 + r) * NN + w*32 + f*16 + l16];

  for (int it = 0; it < 16; ++it){
    const int m0 = it * 128;
    __syncthreads();   // prev iter's Vt reads done before DMA overwrite

    // ---- stage V^T tile via async global->LDS (16B/lane, 4 d-rows/instr) ----
#pragma unroll
    for (int ii = 0; ii < 8; ++ii){
      const int d   = w*32 + ii*4 + quad;          // this lane's d row
      const int gsw = l16 ^ (d & 7);               // xor granule swizzle
      const unsigned short* src = whT_b + (size_t)d * NN + m0 + gsw * 8;
      __builtin_amdgcn_global_load_lds(
          (const __attribute__((address_space(1))) void*)src,
          (__attribute__((address_space(3))) void*)&Vt[(w*32 + ii*4) * 128],
          16, 0, 0);
    }

    // ---- prefetch adj for NEXT iteration (hidden behind this whole iter;
    //      barrier2's vmcnt(0) drain guarantees completion, never a per-load wait)
    int av_n[2][2][4];
    {
      const int mnext = (it < 15) ? (m0 + 128) : 0;   // it=15: harmless dummy
#pragma unroll
      for (int f = 0; f < 2; ++f)
#pragma unroll
        for (int s = 0; s < 2; ++s)
#pragma unroll
          for (int r = 0; r < 4; ++r)
            av_n[f][s][r] = adj_b[(size_t)(qbase + s*16 + quad*4 + r) * NN + mnext + w*32 + f*16 + l16];
    }

    // ---- kf fragments for both f, batched (8 b128 loads in flight) ----
    bf16x8 kf[2][4];
#pragma unroll
    for (int f = 0; f < 2; ++f)
#pragma unroll
      for (int kc = 0; kc < 4; ++kc)
        kf[f][kc] = *(const bf16x8*)(whn_b + (size_t)(m0 + w*32 + f*16 + l16) * DD + kc*32 + quad*8);

    // ---- QK + mask + exp -> P ----
#pragma unroll
    for (int f = 0; f < 2; ++f){
#pragma unroll
      for (int s = 0; s < 2; ++s){
        f32x4 sc = (f32x4){0.f, 0.f, 0.f, 0.f};
#pragma unroll
        for (int kc = 0; kc < 4; ++kc)
          sc = __builtin_amdgcn_mfma_f32_16x16x32_bf16(qf[s][kc], kf[f][kc], sc, 0, 0, 0);
#pragma unroll
        for (int r = 0; r < 4; ++r){
          const int qrow = qbase + s*16 + quad*4 + r;       // C row
          float sv = (qrow < ROWZ) ? 0.f : sc[r];           // row-zeroing bug emulation
          float p32 = (av[f][s][r] > 0) ? __expf(sv) : 0.f;
          unsigned short pb = f2bf(p32);
          lacc[s][r] += bf2f(pb);
          Pw[(s*16 + quad*4 + r) * 40 + f*16 + l16] = pb;   // C-layout -> LDS
        }
      }
    }
    __syncthreads();   // drains vmcnt: Vt ready; av_n complete; P visible

    // ---- PV: out += P[16x32] * V[32x128] per q-subtile ----
#pragma unroll
    for (int s = 0; s < 2; ++s){
      bf16x8 pfr = *(const bf16x8*)&Pw[(s*16 + l16) * 40 + quad*8];  // A-layout read
#pragma unroll
      for (int dt = 0; dt < 8; ++dt){
        const int d  = dt*16 + l16;
        const int gg = (w*4 + quad) ^ (d & 7);
        bf16x8 vf = *(const bf16x8*)&Vt[d * 128 + gg * 8];
        oacc[s][dt] = __builtin_amdgcn_mfma_f32_16x16x32_bf16(pfr, vf, oacc[s][dt], 0, 0, 0);
      }
    }

    // rotate prefetched adj into place
#pragma unroll
    for (int f = 0; f < 2; ++f)
#pragma unroll
      for (int s = 0; s < 2; ++s)
#pragma unroll
        for (int r = 0; r < 4; ++r)
          av[f][s][r] = av_n[f][s][r];
  }

  // ---- l reduction (reuse own wave's Pbuf region as float scratch) ----
  {
    float* lredw = (float*)Pw;
#pragma unroll
    for (int s = 0; s < 2; ++s)
#pragma unroll
      for (int r = 0; r < 4; ++r)
        lredw[(s*16 + quad*4 + r) * 16 + l16] = lacc[s][r];
  }
  __syncthreads();
  if (t < 32){
    float sum = 0.f;
    for (int ww = 0; ww < 4; ++ww){
      const float* lr = (const float*)&Pbuf[ww][0];
#pragma unroll
      for (int c = 0; c < 16; ++c) sum += lr[t * 16 + c];
    }
    linv_s[t] = 1.0f / sum;
  }

  // ---- output reduction across waves (reuse Vt as 32KB float scratch) ----
  float* const ored = (float*)&Vt[0];
  for (int s = 0; s < 2; ++s){
    __syncthreads();   // linv visible / previous pass reads done
#pragma unroll
    for (int dt = 0; dt < 8; ++dt)
#pragma unroll
      for (int r = 0; r < 4; ++r)
        ored[w*2048 + (quad*4 + r)*128 + dt*16 + l16] = oacc[s][dt][r];
    __syncthreads();
#pragma unroll
    for (int j = 0; j < 8; ++j){
      const int o  = j*256 + t;
      const int ql = o >> 7, d = o & 127;
      float v = ored[ql*128 + d] + ored[2048 + ql*128 + d]
              + ored[4096 + ql*128 + d] + ored[6144 + ql*128 + d];
      v *= linv_s[s*16 + ql];
      v = (v > 0.f) ? v : expm1f(v);   // ELU (alpha=1)
      out[(size_t)(b*NN + qbase + s*16 + ql) * DD + d] = v;
    }
  }
}

extern "C" void kernel_launch(void* const* d_in, const int* in_sizes, int n_in,
                              void* d_out, int out_size, void* d_ws, size_t ws_size,
                              hipStream_t stream)
{
  const float* h       = (const float*)d_in[0];
  // d_in[1] = adj  (unused by the reference)
  const int*   adj_eye = (const int*)d_in[2];
  const float* W       = (const float*)d_in[3];
  float*       out     = (float*)d_out;

  unsigned short* whn = (unsigned short*)d_ws;                    // 16384*128 bf16 = 4 MB
  unsigned short* whT = whn + (size_t)16384 * 128;                // 8*128*2048 bf16 = 4 MB

  wh_kernel<<<512, 256, 0, stream>>>(h, W, whn, whT);
  attn_kernel<<<512, 256, 0, stream>>>(whn, whT, adj_eye, out);
}